// Round 20
// baseline (169.839 us; speedup 1.0000x reference)
//
#include <hip/hip_runtime.h>

typedef unsigned int uint;
typedef unsigned short ushort_t;
#define DIM 128
#define NCH 256     // edge chunks for CSR build
#define CGRP 32     // chunks per reduce group
#define NGRP (NCH / CGRP)

typedef __attribute__((ext_vector_type(8))) short bf16x8;
typedef __attribute__((ext_vector_type(4))) float f32x4;
typedef __attribute__((ext_vector_type(2))) float f32x2;

// ---------- bf16 pack helpers ----------
__device__ inline uint packbf2(float a, float b) {
    uint ua = __float_as_uint(a), ub = __float_as_uint(b);
    ua = (ua + 0x7fffu + ((ua >> 16) & 1u)) >> 16;
    ub = (ub + 0x7fffu + ((ub >> 16) & 1u)) & 0xffff0000u;
    return ua | ub;
}

// ---------- histprep: hist (blocks 0..NCH-1) + cvtw (NCH..NCH+63) + zero-out/flags ----------
__global__ __launch_bounds__(256) void histprep_kernel(const int* __restrict__ dst,
        uint* __restrict__ part, int nE, int n, int WPC,
        const float* __restrict__ W1, const float* __restrict__ W2,
        uint* __restrict__ Wt1, uint* __restrict__ Wt2,
        float* __restrict__ out, int outQuads, int* __restrict__ done) {
    int b = blockIdx.x;
    if (b >= NCH) {
        int pb = b - NCH;
        if (pb < 64) {
            const float* W = (pb < 32) ? W1 : W2;
            uint* Wt = (pb < 32) ? Wt1 : Wt2;
            int idx = (pb & 31) * 256 + threadIdx.x;  // 0..8191
            int c = idx >> 6;
            int kw = idx & 63;
            float a = W[(2 * kw) * DIM + c];
            float bb = W[(2 * kw + 1) * DIM + c];
            Wt[c * 64 + kw] = packbf2(a, bb);
        } else {
            if (pb == 64 && threadIdx.x == 0) *done = 0;
            int q = (pb - 64) * 256 + threadIdx.x;
            if (q < outQuads) ((float4*)out)[q] = make_float4(0.f, 0.f, 0.f, 0.f);
        }
        return;
    }
    extern __shared__ uint h[];
    const int nw4 = (n + 3) >> 2;
    for (int j = threadIdx.x; j < nw4; j += 256) h[j] = 0;
    __syncthreads();
    int chunk = (((nE + NCH - 1) / NCH) + 3) & ~3;
    int lo = b * chunk;
    int hi = min(nE, lo + chunk);
    int hiA = lo + ((hi - lo) & ~3);
    for (int e = lo + threadIdx.x * 4; e < hiA; e += 1024) {
        int4 v = *(const int4*)(dst + e);
        atomicAdd(&h[v.x >> 2], 1u << ((v.x & 3) * 8));
        atomicAdd(&h[v.y >> 2], 1u << ((v.y & 3) * 8));
        atomicAdd(&h[v.z >> 2], 1u << ((v.z & 3) * 8));
        atomicAdd(&h[v.w >> 2], 1u << ((v.w & 3) * 8));
    }
    for (int e = hiA + threadIdx.x; e < hi; e += 256) {
        int d = dst[e];
        atomicAdd(&h[d >> 2], 1u << ((d & 3) * 8));
    }
    __syncthreads();
    uint* pw = part + (size_t)b * WPC;
    for (int j = threadIdx.x; j < nw4; j += 256) pw[j] = h[j];
}

// ---------- reduceA: per (word-range, chunk-group): intra-group prefix + group sum ----------
__global__ void reduceA_kernel(uint* __restrict__ part, uint* __restrict__ gsum,
                               int n, int WPC) {
    int j = blockIdx.x * blockDim.x + threadIdx.x;
    int nw4 = (n + 3) >> 2;
    if (j >= nw4) return;
    int g = blockIdx.y;
    int c0 = g * CGRP;
    uint run = 0;
#pragma unroll 8
    for (int c = c0; c < c0 + CGRP; ++c) {
        size_t idx = (size_t)c * WPC + j;
        uint v = part[idx];
        part[idx] = run;
        run += v;  // packed u8 add; per-lane totals < 256
    }
    gsum[(size_t)g * WPC + j] = run;
}

__device__ inline int wave_incl_scan(int v) {
    int lane = threadIdx.x & 63;
#pragma unroll
    for (int off = 1; off < 64; off <<= 1) {
        int u = __shfl_up(v, off, 64);
        if (lane >= off) v += u;
    }
    return v;
}

// ---------- gsumscan: gsum chunk-prefix -> deg + block sums + last-block bsum scan ----------
__global__ __launch_bounds__(256) void gsumscan_kernel(uint* __restrict__ gsum,
        int* __restrict__ deg, int* __restrict__ bsum, int* __restrict__ rowptr,
        int* __restrict__ done, int n, int nb, int WPC) {
    __shared__ int wsum[4];
    __shared__ int lastFlag;
    int t = threadIdx.x;
    int j = blockIdx.x * 256 + t;
    int nw4 = (n + 3) >> 2;
    uint run = 0;
    if (j < nw4) {
#pragma unroll
        for (int g = 0; g < NGRP; ++g) {
            size_t idx = (size_t)g * WPC + j;
            uint v = gsum[idx];
            gsum[idx] = run;
            run += v;
        }
        int base = 4 * j;
        deg[base] = (int)(run & 0xffu);
        if (base + 1 < n) deg[base + 1] = (int)((run >> 8) & 0xffu);
        if (base + 2 < n) deg[base + 2] = (int)((run >> 16) & 0xffu);
        if (base + 3 < n) deg[base + 3] = (int)(run >> 24);
    }
    int s = (int)((run & 0xffu) + ((run >> 8) & 0xffu) + ((run >> 16) & 0xffu) + (run >> 24));
#pragma unroll
    for (int off = 32; off > 0; off >>= 1) s += __shfl_down(s, off, 64);
    if ((t & 63) == 0) wsum[t >> 6] = s;
    __syncthreads();
    if (t == 0) {
        bsum[blockIdx.x] = wsum[0] + wsum[1] + wsum[2] + wsum[3];
        __threadfence();
        int r = atomicAdd(done, 1);
        lastFlag = (r == nb - 1);
    }
    __syncthreads();
    if (lastFlag && t < 64) {
        __threadfence();
        int vv = (t < nb) ? bsum[t] : 0;
        int incl = wave_incl_scan(vv);
        if (t < nb) bsum[t] = incl - vv;
        if (t == 63) rowptr[n] = incl;
    }
}

// ---------- scan3: node-level exclusive scan + dinv ----------
__global__ void scan3_kernel(const int* __restrict__ deg, const int* __restrict__ bsum,
                             int* __restrict__ rowptr, float* __restrict__ dinv, int n) {
    __shared__ int wsum[16];
    int t = threadIdx.x;
    int i = blockIdx.x * 1024 + t;
    int v = (i < n) ? deg[i] : 0;
    int incl = wave_incl_scan(v);
    int wid = t >> 6;
    if ((t & 63) == 63) wsum[wid] = incl;
    __syncthreads();
    if (t == 0) {
        int run = 0;
#pragma unroll
        for (int w = 0; w < 16; ++w) { int x = wsum[w]; wsum[w] = run; run += x; }
    }
    __syncthreads();
    if (i < n) {
        rowptr[i] = incl - v + wsum[wid] + bsum[blockIdx.x];
        dinv[i] = rsqrtf((float)(v + 1));  // +1 self-loop
    }
}

// ---------- CSR fill: u8x4 LDS cursor; csr stores BYTE offsets (src*256) ----------
__global__ __launch_bounds__(256) void fill_kernel(const int* __restrict__ src,
                                                   const int* __restrict__ dst,
                                                   const uint* __restrict__ part,
                                                   const uint* __restrict__ gsum,
                                                   const int* __restrict__ rowptr,
                                                   int* __restrict__ csr,
                                                   int nE, int n, int WPC) {
    extern __shared__ uint cur[];
    const int nw4 = (n + 3) >> 2;
    for (int j = threadIdx.x; j < nw4; j += 256) cur[j] = 0;
    __syncthreads();
    const uint* P = part + (size_t)blockIdx.x * WPC;
    const uint* G = gsum + (size_t)(blockIdx.x / CGRP) * WPC;
    int chunk = (((nE + NCH - 1) / NCH) + 3) & ~3;
    int lo = blockIdx.x * chunk;
    int hi = min(nE, lo + chunk);
    int hiA = lo + ((hi - lo) & ~3);
    for (int e = lo + threadIdx.x * 4; e < hiA; e += 1024) {
        int4 d4 = *(const int4*)(dst + e);
        int4 s4 = *(const int4*)(src + e);
        int dd[4] = {d4.x, d4.y, d4.z, d4.w};
        int ss[4] = {s4.x, s4.y, s4.z, s4.w};
#pragma unroll
        for (int k = 0; k < 4; ++k) {
            int d = dd[k];
            uint sh = (uint)(d & 3) * 8u;
            uint old = atomicAdd(&cur[d >> 2], 1u << sh);
            uint local = (old >> sh) & 0xffu;
            uint pre = ((P[d >> 2] >> sh) & 0xffu) + ((G[d >> 2] >> sh) & 0xffu);
            csr[rowptr[d] + (int)pre + (int)local] = ss[k] << 8;
        }
    }
    for (int e = hiA + threadIdx.x; e < hi; e += 256) {
        int d = dst[e];
        uint sh = (uint)(d & 3) * 8u;
        uint old = atomicAdd(&cur[d >> 2], 1u << sh);
        uint local = (old >> sh) & 0xffu;
        uint pre = ((P[d >> 2] >> sh) & 0xffu) + ((G[d >> 2] >> sh) & 0xffu);
        csr[rowptr[d] + (int)pre + (int)local] = src[e] << 8;
    }
}

// ---------- MFMA GEMM: Hs8[r] = fp8( (X[r,:] @ W) * dinv[r] ) ----------
template <bool F32IN>
__global__ __launch_bounds__(256) void gemm_mfma_kernel(const void* __restrict__ Xv,
        const uint* __restrict__ Wt, const float* __restrict__ dinv,
        char* __restrict__ Hs8, int M) {
    __shared__ __align__(16) uint lw[8192];  // 32KB Wt[c][k]
    __shared__ __align__(16) uint lx[4096];  // 16KB X[r][k]
    const int tid = threadIdx.x;
    const int brow = blockIdx.x * 64;
#pragma unroll
    for (int p = 0; p < 16; ++p) {
        int j = p * 256 + tid;
        int r = j >> 6, kw = j & 63;
        int row = brow + r;
        uint v = 0u;
        if (row < M) {
            if (F32IN) {
                float2 f = ((const float2*)Xv)[(size_t)row * 64 + kw];
                v = packbf2(f.x, f.y);
            } else {
                v = ((const uint*)Xv)[(size_t)row * 64 + kw];
            }
        }
        lx[(r << 6) | (((kw >> 2) ^ (r & 7)) << 2) | (kw & 3)] = v;
    }
#pragma unroll
    for (int p = 0; p < 32; ++p) {
        int j = p * 256 + tid;
        int c = j >> 6, kw = j & 63;
        lw[(c << 6) | (((kw >> 2) ^ (c & 7)) << 2) | (kw & 3)] = Wt[j];
    }
    __syncthreads();
    const int wave = tid >> 6, l = tid & 63;
    const int hl = l >> 4;
    const int arow = (wave << 4) | (l & 15);
    f32x4 acc[8];
#pragma unroll
    for (int f = 0; f < 8; ++f) acc[f] = (f32x4){0.f, 0.f, 0.f, 0.f};
#pragma unroll
    for (int ks = 0; ks < 4; ++ks) {
        int ua = (ks << 2) + hl;  // 16B-unit index along K
        bf16x8 af = *(const bf16x8*)&lx[(arow << 6) | ((ua ^ (arow & 7)) << 2)];
#pragma unroll
        for (int f = 0; f < 8; ++f) {
            int bcol = (f << 4) | (l & 15);
            bf16x8 bf = *(const bf16x8*)&lw[(bcol << 6) | ((ua ^ (bcol & 7)) << 2)];
            acc[f] = __builtin_amdgcn_mfma_f32_16x16x32_bf16(af, bf, acc[f], 0, 0, 0);
        }
    }
    // epilogue: D col = lane&15, row = (lane>>4)*4 + reg; fp8 pack of (col, col+1)
    const int rbase = brow + (wave << 4) + (hl << 2);
    float dv[4];
#pragma unroll
    for (int r = 0; r < 4; ++r) dv[r] = (rbase + r < M) ? dinv[rbase + r] : 0.f;
#pragma unroll
    for (int f = 0; f < 8; ++f) {
#pragma unroll
        for (int r = 0; r < 4; ++r) {
            float mine = acc[f][r] * dv[r];
            float other = __shfl_xor(mine, 1, 64);
            if (!(l & 1)) {
                int row = rbase + r;
                if (row < M) {
                    int pk = __builtin_amdgcn_cvt_pk_fp8_f32(mine, other, 0, false);
                    *(ushort_t*)(Hs8 + (size_t)row * 128 + ((f << 4) | (l & 15))) =
                        (ushort_t)(pk & 0xffff);
                }
            }
        }
    }
}

// ---------- fp8 row accumulate: uint2 = 8 dims ----------
__device__ inline void g2_acc(uint2 u, float* ax, float* ay) {
    f32x2 f0 = __builtin_amdgcn_cvt_pk_f32_fp8((int)u.x, false);
    f32x2 f1 = __builtin_amdgcn_cvt_pk_f32_fp8((int)u.x, true);
    f32x2 f2 = __builtin_amdgcn_cvt_pk_f32_fp8((int)u.y, false);
    f32x2 f3 = __builtin_amdgcn_cvt_pk_f32_fp8((int)u.y, true);
    ax[0] += f0.x; ay[0] += f0.y;
    ax[1] += f1.x; ay[1] += f1.y;
    ax[2] += f2.x; ay[2] += f2.y;
    ax[3] += f3.x; ay[3] += f3.y;
}

// ---------- pipelined fp8 gather: csr indices prefetched one iteration ahead ----------
__device__ inline void gather_fp8(const char* __restrict__ Hs8, const int* __restrict__ csr,
                                  int e, int end, int slot, int q8, float* ax, float* ay) {
    int c0 = 0, c1 = 0, c2 = 0, c3 = 0;
    bool have = (e + 16 <= end);
    if (have) {
        c0 = csr[e + slot]; c1 = csr[e + 4 + slot];
        c2 = csr[e + 8 + slot]; c3 = csr[e + 12 + slot];
    }
    while (have) {
        int ne = e + 16;
        bool nhave = (ne + 16 <= end);
        int n0 = 0, n1 = 0, n2 = 0, n3 = 0;
        if (nhave) {
            n0 = csr[ne + slot]; n1 = csr[ne + 4 + slot];
            n2 = csr[ne + 8 + slot]; n3 = csr[ne + 12 + slot];
        }
        uint2 u0 = *(const uint2*)(Hs8 + (uint)((c0 >> 1) + q8));
        uint2 u1 = *(const uint2*)(Hs8 + (uint)((c1 >> 1) + q8));
        uint2 u2 = *(const uint2*)(Hs8 + (uint)((c2 >> 1) + q8));
        uint2 u3 = *(const uint2*)(Hs8 + (uint)((c3 >> 1) + q8));
        g2_acc(u0, ax, ay); g2_acc(u1, ax, ay);
        g2_acc(u2, ax, ay); g2_acc(u3, ax, ay);
        e = ne; c0 = n0; c1 = n1; c2 = n2; c3 = n3; have = nhave;
    }
    for (; e + 4 <= end; e += 4) {
        int o = csr[e + slot];
        uint2 u = *(const uint2*)(Hs8 + (uint)((o >> 1) + q8));
        g2_acc(u, ax, ay);
    }
    int rem = end - e;
    if (slot < rem) {
        int o = csr[e + slot];
        uint2 u = *(const uint2*)(Hs8 + (uint)((o >> 1) + q8));
        g2_acc(u, ax, ay);
    }
}

// ---------- gather layer 1 (fp8 table): slot-lane wide loads; bf16 A out ----------
__global__ __launch_bounds__(256) void gather1_kernel(const char* __restrict__ Hs8,
        const int* __restrict__ rowptr, const int* __restrict__ csr,
        const float* __restrict__ dinv, const float* __restrict__ b1,
        uint* __restrict__ A, int n) {
    int i = blockIdx.x * 4 + (threadIdx.x >> 6);
    int l = threadIdx.x & 63;
    int slot = l >> 4, q = l & 15;
    if (i >= n) return;
    const int q8 = q * 8;
    float ax[4] = {0.f, 0.f, 0.f, 0.f}, ay[4] = {0.f, 0.f, 0.f, 0.f};
    if (slot == 0) {  // self-loop
        uint2 u = *(const uint2*)(Hs8 + (size_t)i * 128 + q8);
        g2_acc(u, ax, ay);
    }
    gather_fp8(Hs8, csr, rowptr[i], rowptr[i + 1], slot, q8, ax, ay);
#pragma unroll
    for (int k = 0; k < 4; ++k) {
        ax[k] += __shfl_xor(ax[k], 16, 64); ay[k] += __shfl_xor(ay[k], 16, 64);
        ax[k] += __shfl_xor(ax[k], 32, 64); ay[k] += __shfl_xor(ay[k], 32, 64);
    }
    if (slot == 0) {
        float di = dinv[i];
        const float2* bp = (const float2*)(b1 + 8 * q);
        float2 b0 = bp[0], b1v = bp[1], b2v = bp[2], b3v = bp[3];
        uint4 o;
        o.x = packbf2(fmaxf(di * ax[0] + b0.x, 0.f), fmaxf(di * ay[0] + b0.y, 0.f));
        o.y = packbf2(fmaxf(di * ax[1] + b1v.x, 0.f), fmaxf(di * ay[1] + b1v.y, 0.f));
        o.z = packbf2(fmaxf(di * ax[2] + b2v.x, 0.f), fmaxf(di * ay[2] + b2v.y, 0.f));
        o.w = packbf2(fmaxf(di * ax[3] + b3v.x, 0.f), fmaxf(di * ay[3] + b3v.y, 0.f));
        *(uint4*)(A + (size_t)i * 64 + q * 4) = o;
    }
}

// ---------- gather layer 2 (fp8 table) + pooled-merge atomics ----------
__global__ __launch_bounds__(512) void gather2_kernel(const char* __restrict__ Hs8,
        const int* __restrict__ rowptr, const int* __restrict__ csr,
        const float* __restrict__ dinv, const int* __restrict__ batch,
        float* __restrict__ out, int n) {
    __shared__ float sh[8][DIM];
    __shared__ int sgid[8];
    int w = threadIdx.x >> 6;
    int l = threadIdx.x & 63;
    int slot = l >> 4, q = l & 15;
    int i = blockIdx.x * 8 + w;
    if (i < n) {
        const int q8 = q * 8;
        float ax[4] = {0.f, 0.f, 0.f, 0.f}, ay[4] = {0.f, 0.f, 0.f, 0.f};
        if (slot == 0) {  // self-loop
            uint2 u = *(const uint2*)(Hs8 + (size_t)i * 128 + q8);
            g2_acc(u, ax, ay);
        }
        gather_fp8(Hs8, csr, rowptr[i], rowptr[i + 1], slot, q8, ax, ay);
#pragma unroll
        for (int k = 0; k < 4; ++k) {
            ax[k] += __shfl_xor(ax[k], 16, 64); ay[k] += __shfl_xor(ay[k], 16, 64);
            ax[k] += __shfl_xor(ax[k], 32, 64); ay[k] += __shfl_xor(ay[k], 32, 64);
        }
        if (slot == 0) {
            float di = dinv[i];
            float* sp = &sh[w][8 * q];
            sp[0] = di * ax[0]; sp[1] = di * ay[0];
            sp[2] = di * ax[1]; sp[3] = di * ay[1];
            sp[4] = di * ax[2]; sp[5] = di * ay[2];
            sp[6] = di * ax[3]; sp[7] = di * ay[3];
            if (q == 0) sgid[w] = batch[i];
        }
    } else if (l == 0) {
        sgid[w] = -1;
    }
    __syncthreads();
    if (threadIdx.x < DIM) {
        int d = threadIdx.x;
        int curg = -1; float run = 0.0f;
#pragma unroll
        for (int r = 0; r < 8; ++r) {
            int g = sgid[r];
            if (g < 0) continue;
            if (g != curg) {
                if (curg >= 0) atomicAdd(&out[(size_t)curg * DIM + d], run);
                curg = g; run = sh[r][d];
            } else {
                run += sh[r][d];
            }
        }
        if (curg >= 0) atomicAdd(&out[(size_t)curg * DIM + d], run);
    }
}

// ---------- finalize: cnt via binary search on sorted batch ----------
__global__ void fin_kernel(float* __restrict__ out, const int* __restrict__ batch,
                           const float* __restrict__ b2, int n, int nG) {
    int tid = blockIdx.x * blockDim.x + threadIdx.x;
    int g = tid >> 7;
    int d = tid & (DIM - 1);
    if (g >= nG) return;
    int lo = 0, hi = n;
    while (lo < hi) { int m = (lo + hi) >> 1; if (batch[m] < g) lo = m + 1; else hi = m; }
    int s0 = lo;
    hi = n;
    while (lo < hi) { int m = (lo + hi) >> 1; if (batch[m] < g + 1) lo = m + 1; else hi = m; }
    float c = (float)(lo - s0);
    out[tid] = (out[tid] + c * b2[d]) / fmaxf(c, 1.0f);
}

extern "C" void kernel_launch(void* const* d_in, const int* in_sizes, int n_in,
                              void* d_out, int out_size, void* d_ws, size_t ws_size,
                              hipStream_t stream) {
    const float* x     = (const float*)d_in[0];
    const int*   ei    = (const int*)d_in[1];
    const int*   batch = (const int*)d_in[2];
    const float* W1    = (const float*)d_in[3];
    const float* b1    = (const float*)d_in[4];
    const float* W2    = (const float*)d_in[5];
    const float* b2    = (const float*)d_in[6];
    float* out = (float*)d_out;

    const int n  = in_sizes[0] / DIM;   // 50000
    const int nE = in_sizes[1] / 2;     // 800000
    const int nG = out_size / DIM;      // 512

    const int* src = ei;
    const int* dst = ei + nE;

    const int nw4 = (n + 3) >> 2;                 // u8x4-packed words per chunk
    const int WPC = (nw4 + 3) & ~3;
    const size_t packBytes = (size_t)n * 64 * sizeof(uint);   // 12.8 MB (A bf16)
    const size_t partBytes = (size_t)NCH * WPC * 4;           // 12.8 MB
    const size_t ldsBytes  = (size_t)nw4 * 4;                 // 50 KB

    char* ws = (char*)d_ws;
    size_t off = 0;
    auto alloc = [&](size_t bytes) { void* p = ws + off; off = (off + bytes + 255) & ~(size_t)255; return p; };
    // part (CSR phase) aliases Hs8 (6.4MB fp8 tables, both layers); A at +12.8MB.
    size_t bigBytes = partBytes > 2 * packBytes ? partBytes : 2 * packBytes;
    char*  big    = (char*)alloc(bigBytes);
    uint*  part   = (uint*)big;
    char*  Hs8    = big;
    uint*  A      = (uint*)(big + packBytes);
    uint*  gsum   = (uint*)alloc((size_t)NGRP * WPC * 4);     // 400 KB (live through fill)
    int*   deg    = (int*)alloc((size_t)n * 4);
    int*   done   = (int*)alloc(256);
    float* dinv   = (float*)alloc((size_t)n * 4);
    int*   rowptr = (int*)alloc((size_t)(n + 1) * 4);
    int*   bsum   = (int*)alloc(256);
    uint*  Wt1    = (uint*)alloc(8192 * 4);
    uint*  Wt2    = (uint*)alloc(8192 * 4);
    int*   csr    = (int*)alloc((size_t)nE * 4);

    const int B = 256;
    const int nb = (n + 1023) / 1024;  // 49
    const int nwb = (nw4 + B - 1) / B; // 49
    const int outQuads = out_size / 4;

    histprep_kernel<<<NCH + 128, 256, ldsBytes, stream>>>(dst, part, nE, n, WPC,
                                                          W1, W2, Wt1, Wt2, out, outQuads, done);
    reduceA_kernel<<<dim3(nwb, NGRP), B, 0, stream>>>(part, gsum, n, WPC);
    gsumscan_kernel<<<nb, 256, 0, stream>>>(gsum, deg, bsum, rowptr, done, n, nb, WPC);
    scan3_kernel<<<nb, 1024, 0, stream>>>(deg, bsum, rowptr, dinv, n);
    fill_kernel<<<NCH, 256, ldsBytes, stream>>>(src, dst, part, gsum, rowptr, csr, nE, n, WPC);

    // Layer 1: f32 x -> fp8 Hs8 table -> bf16 A
    gemm_mfma_kernel<true><<<(n + 63) / 64, 256, 0, stream>>>(x, Wt1, dinv, Hs8, n);
    gather1_kernel<<<(n + 3) / 4, 256, 0, stream>>>(Hs8, rowptr, csr, dinv, b1, A, n);

    // Layer 2: bf16 A -> fp8 Hs8 table -> pooled out
    gemm_mfma_kernel<false><<<(n + 63) / 64, 256, 0, stream>>>(A, Wt2, dinv, Hs8, n);
    gather2_kernel<<<(n + 7) / 8, 512, 0, stream>>>(Hs8, rowptr, csr, dinv, batch, out, n);

    fin_kernel<<<(nG * DIM + B - 1) / B, B, 0, stream>>>(out, batch, b2, n, nG);
}

// Round 21
// 163.278 us; speedup vs baseline: 1.0402x; 1.0402x over previous
//
#include <hip/hip_runtime.h>

typedef unsigned int uint;
typedef unsigned short ushort_t;
#define DIM 128
#define NCH 256     // edge chunks for CSR build
#define CGRP 32     // chunks per reduce group
#define NGRP (NCH / CGRP)

typedef __attribute__((ext_vector_type(8))) short bf16x8;
typedef __attribute__((ext_vector_type(4))) float f32x4;
typedef __attribute__((ext_vector_type(2))) float f32x2;

// ---------- bf16 pack helpers ----------
__device__ inline uint packbf2(float a, float b) {
    uint ua = __float_as_uint(a), ub = __float_as_uint(b);
    ua = (ua + 0x7fffu + ((ua >> 16) & 1u)) >> 16;
    ub = (ub + 0x7fffu + ((ub >> 16) & 1u)) & 0xffff0000u;
    return ua | ub;
}

// ---------- histprep: hist (blocks 0..NCH-1) + cvtw (NCH..NCH+63) + zero-out/flags ----------
__global__ __launch_bounds__(256) void histprep_kernel(const int* __restrict__ dst,
        uint* __restrict__ part, int nE, int n, int WPC,
        const float* __restrict__ W1, const float* __restrict__ W2,
        uint* __restrict__ Wt1, uint* __restrict__ Wt2,
        float* __restrict__ out, int outQuads, int* __restrict__ done) {
    int b = blockIdx.x;
    if (b >= NCH) {
        int pb = b - NCH;
        if (pb < 64) {
            const float* W = (pb < 32) ? W1 : W2;
            uint* Wt = (pb < 32) ? Wt1 : Wt2;
            int idx = (pb & 31) * 256 + threadIdx.x;  // 0..8191
            int c = idx >> 6;
            int kw = idx & 63;
            float a = W[(2 * kw) * DIM + c];
            float bb = W[(2 * kw + 1) * DIM + c];
            Wt[c * 64 + kw] = packbf2(a, bb);
        } else {
            if (pb == 64 && threadIdx.x == 0) *done = 0;
            int q = (pb - 64) * 256 + threadIdx.x;
            if (q < outQuads) ((float4*)out)[q] = make_float4(0.f, 0.f, 0.f, 0.f);
        }
        return;
    }
    extern __shared__ uint h[];
    const int nw4 = (n + 3) >> 2;
    for (int j = threadIdx.x; j < nw4; j += 256) h[j] = 0;
    __syncthreads();
    int chunk = (((nE + NCH - 1) / NCH) + 3) & ~3;
    int lo = b * chunk;
    int hi = min(nE, lo + chunk);
    int hiA = lo + ((hi - lo) & ~3);
    for (int e = lo + threadIdx.x * 4; e < hiA; e += 1024) {
        int4 v = *(const int4*)(dst + e);
        atomicAdd(&h[v.x >> 2], 1u << ((v.x & 3) * 8));
        atomicAdd(&h[v.y >> 2], 1u << ((v.y & 3) * 8));
        atomicAdd(&h[v.z >> 2], 1u << ((v.z & 3) * 8));
        atomicAdd(&h[v.w >> 2], 1u << ((v.w & 3) * 8));
    }
    for (int e = hiA + threadIdx.x; e < hi; e += 256) {
        int d = dst[e];
        atomicAdd(&h[d >> 2], 1u << ((d & 3) * 8));
    }
    __syncthreads();
    uint* pw = part + (size_t)b * WPC;
    for (int j = threadIdx.x; j < nw4; j += 256) pw[j] = h[j];
}

// ---------- reduceA: per (word-range, chunk-group): intra-group prefix + group sum ----------
__global__ void reduceA_kernel(uint* __restrict__ part, uint* __restrict__ gsum,
                               int n, int WPC) {
    int j = blockIdx.x * blockDim.x + threadIdx.x;
    int nw4 = (n + 3) >> 2;
    if (j >= nw4) return;
    int g = blockIdx.y;
    int c0 = g * CGRP;
    uint run = 0;
#pragma unroll 8
    for (int c = c0; c < c0 + CGRP; ++c) {
        size_t idx = (size_t)c * WPC + j;
        uint v = part[idx];
        part[idx] = run;
        run += v;  // packed u8 add; per-lane totals < 256
    }
    gsum[(size_t)g * WPC + j] = run;
}

__device__ inline int wave_incl_scan(int v) {
    int lane = threadIdx.x & 63;
#pragma unroll
    for (int off = 1; off < 64; off <<= 1) {
        int u = __shfl_up(v, off, 64);
        if (lane >= off) v += u;
    }
    return v;
}

// ---------- gsumscan: gsum chunk-prefix -> deg + block sums + last-block bsum scan ----------
__global__ __launch_bounds__(256) void gsumscan_kernel(uint* __restrict__ gsum,
        int* __restrict__ deg, int* __restrict__ bsum, int* __restrict__ rowptr,
        int* __restrict__ done, int n, int nb, int WPC) {
    __shared__ int wsum[4];
    __shared__ int lastFlag;
    int t = threadIdx.x;
    int j = blockIdx.x * 256 + t;
    int nw4 = (n + 3) >> 2;
    uint run = 0;
    if (j < nw4) {
#pragma unroll
        for (int g = 0; g < NGRP; ++g) {
            size_t idx = (size_t)g * WPC + j;
            uint v = gsum[idx];
            gsum[idx] = run;
            run += v;
        }
        int base = 4 * j;
        deg[base] = (int)(run & 0xffu);
        if (base + 1 < n) deg[base + 1] = (int)((run >> 8) & 0xffu);
        if (base + 2 < n) deg[base + 2] = (int)((run >> 16) & 0xffu);
        if (base + 3 < n) deg[base + 3] = (int)(run >> 24);
    }
    int s = (int)((run & 0xffu) + ((run >> 8) & 0xffu) + ((run >> 16) & 0xffu) + (run >> 24));
#pragma unroll
    for (int off = 32; off > 0; off >>= 1) s += __shfl_down(s, off, 64);
    if ((t & 63) == 0) wsum[t >> 6] = s;
    __syncthreads();
    if (t == 0) {
        bsum[blockIdx.x] = wsum[0] + wsum[1] + wsum[2] + wsum[3];
        __threadfence();
        int r = atomicAdd(done, 1);
        lastFlag = (r == nb - 1);
    }
    __syncthreads();
    if (lastFlag && t < 64) {
        __threadfence();
        int vv = (t < nb) ? bsum[t] : 0;
        int incl = wave_incl_scan(vv);
        if (t < nb) bsum[t] = incl - vv;
        if (t == 63) rowptr[n] = incl;
    }
}

// ---------- scan3: node-level exclusive scan + dinv ----------
__global__ void scan3_kernel(const int* __restrict__ deg, const int* __restrict__ bsum,
                             int* __restrict__ rowptr, float* __restrict__ dinv, int n) {
    __shared__ int wsum[16];
    int t = threadIdx.x;
    int i = blockIdx.x * 1024 + t;
    int v = (i < n) ? deg[i] : 0;
    int incl = wave_incl_scan(v);
    int wid = t >> 6;
    if ((t & 63) == 63) wsum[wid] = incl;
    __syncthreads();
    if (t == 0) {
        int run = 0;
#pragma unroll
        for (int w = 0; w < 16; ++w) { int x = wsum[w]; wsum[w] = run; run += x; }
    }
    __syncthreads();
    if (i < n) {
        rowptr[i] = incl - v + wsum[wid] + bsum[blockIdx.x];
        dinv[i] = rsqrtf((float)(v + 1));  // +1 self-loop
    }
}

// ---------- CSR fill: u8x4 LDS cursor; csr stores BYTE offsets (src*256) ----------
__global__ __launch_bounds__(256) void fill_kernel(const int* __restrict__ src,
                                                   const int* __restrict__ dst,
                                                   const uint* __restrict__ part,
                                                   const uint* __restrict__ gsum,
                                                   const int* __restrict__ rowptr,
                                                   int* __restrict__ csr,
                                                   int nE, int n, int WPC) {
    extern __shared__ uint cur[];
    const int nw4 = (n + 3) >> 2;
    for (int j = threadIdx.x; j < nw4; j += 256) cur[j] = 0;
    __syncthreads();
    const uint* P = part + (size_t)blockIdx.x * WPC;
    const uint* G = gsum + (size_t)(blockIdx.x / CGRP) * WPC;
    int chunk = (((nE + NCH - 1) / NCH) + 3) & ~3;
    int lo = blockIdx.x * chunk;
    int hi = min(nE, lo + chunk);
    int hiA = lo + ((hi - lo) & ~3);
    for (int e = lo + threadIdx.x * 4; e < hiA; e += 1024) {
        int4 d4 = *(const int4*)(dst + e);
        int4 s4 = *(const int4*)(src + e);
        int dd[4] = {d4.x, d4.y, d4.z, d4.w};
        int ss[4] = {s4.x, s4.y, s4.z, s4.w};
#pragma unroll
        for (int k = 0; k < 4; ++k) {
            int d = dd[k];
            uint sh = (uint)(d & 3) * 8u;
            uint old = atomicAdd(&cur[d >> 2], 1u << sh);
            uint local = (old >> sh) & 0xffu;
            uint pre = ((P[d >> 2] >> sh) & 0xffu) + ((G[d >> 2] >> sh) & 0xffu);
            csr[rowptr[d] + (int)pre + (int)local] = ss[k] << 8;
        }
    }
    for (int e = hiA + threadIdx.x; e < hi; e += 256) {
        int d = dst[e];
        uint sh = (uint)(d & 3) * 8u;
        uint old = atomicAdd(&cur[d >> 2], 1u << sh);
        uint local = (old >> sh) & 0xffu;
        uint pre = ((P[d >> 2] >> sh) & 0xffu) + ((G[d >> 2] >> sh) & 0xffu);
        csr[rowptr[d] + (int)pre + (int)local] = src[e] << 8;
    }
}

// ---------- MFMA GEMM: Hs8[r] = fp8( (X[r,:] @ W) * dinv[r] ) ----------
template <bool F32IN>
__global__ __launch_bounds__(256) void gemm_mfma_kernel(const void* __restrict__ Xv,
        const uint* __restrict__ Wt, const float* __restrict__ dinv,
        char* __restrict__ Hs8, int M) {
    __shared__ __align__(16) uint lw[8192];  // 32KB Wt[c][k]
    __shared__ __align__(16) uint lx[4096];  // 16KB X[r][k]
    const int tid = threadIdx.x;
    const int brow = blockIdx.x * 64;
#pragma unroll
    for (int p = 0; p < 16; ++p) {
        int j = p * 256 + tid;
        int r = j >> 6, kw = j & 63;
        int row = brow + r;
        uint v = 0u;
        if (row < M) {
            if (F32IN) {
                float2 f = ((const float2*)Xv)[(size_t)row * 64 + kw];
                v = packbf2(f.x, f.y);
            } else {
                v = ((const uint*)Xv)[(size_t)row * 64 + kw];
            }
        }
        lx[(r << 6) | (((kw >> 2) ^ (r & 7)) << 2) | (kw & 3)] = v;
    }
#pragma unroll
    for (int p = 0; p < 32; ++p) {
        int j = p * 256 + tid;
        int c = j >> 6, kw = j & 63;
        lw[(c << 6) | (((kw >> 2) ^ (c & 7)) << 2) | (kw & 3)] = Wt[j];
    }
    __syncthreads();
    const int wave = tid >> 6, l = tid & 63;
    const int hl = l >> 4;
    const int arow = (wave << 4) | (l & 15);
    f32x4 acc[8];
#pragma unroll
    for (int f = 0; f < 8; ++f) acc[f] = (f32x4){0.f, 0.f, 0.f, 0.f};
#pragma unroll
    for (int ks = 0; ks < 4; ++ks) {
        int ua = (ks << 2) + hl;  // 16B-unit index along K
        bf16x8 af = *(const bf16x8*)&lx[(arow << 6) | ((ua ^ (arow & 7)) << 2)];
#pragma unroll
        for (int f = 0; f < 8; ++f) {
            int bcol = (f << 4) | (l & 15);
            bf16x8 bf = *(const bf16x8*)&lw[(bcol << 6) | ((ua ^ (bcol & 7)) << 2)];
            acc[f] = __builtin_amdgcn_mfma_f32_16x16x32_bf16(af, bf, acc[f], 0, 0, 0);
        }
    }
    // epilogue: D col = lane&15, row = (lane>>4)*4 + reg; fp8 pack of (col, col+1)
    const int rbase = brow + (wave << 4) + (hl << 2);
    float dv[4];
#pragma unroll
    for (int r = 0; r < 4; ++r) dv[r] = (rbase + r < M) ? dinv[rbase + r] : 0.f;
#pragma unroll
    for (int f = 0; f < 8; ++f) {
#pragma unroll
        for (int r = 0; r < 4; ++r) {
            float mine = acc[f][r] * dv[r];
            float other = __shfl_xor(mine, 1, 64);
            if (!(l & 1)) {
                int row = rbase + r;
                if (row < M) {
                    int pk = __builtin_amdgcn_cvt_pk_fp8_f32(mine, other, 0, false);
                    *(ushort_t*)(Hs8 + (size_t)row * 128 + ((f << 4) | (l & 15))) =
                        (ushort_t)(pk & 0xffff);
                }
            }
        }
    }
}

// ---------- fp8 row accumulate: uint2 = 8 dims ----------
__device__ inline void g2_acc(uint2 u, float* ax, float* ay) {
    f32x2 f0 = __builtin_amdgcn_cvt_pk_f32_fp8((int)u.x, false);
    f32x2 f1 = __builtin_amdgcn_cvt_pk_f32_fp8((int)u.x, true);
    f32x2 f2 = __builtin_amdgcn_cvt_pk_f32_fp8((int)u.y, false);
    f32x2 f3 = __builtin_amdgcn_cvt_pk_f32_fp8((int)u.y, true);
    ax[0] += f0.x; ay[0] += f0.y;
    ax[1] += f1.x; ay[1] += f1.y;
    ax[2] += f2.x; ay[2] += f2.y;
    ax[3] += f3.x; ay[3] += f3.y;
}

// ---------- simple fp8 gather loop (r18-proven) ----------
__device__ inline void gather_fp8(const char* __restrict__ Hs8, const int* __restrict__ csr,
                                  int e, int end, int slot, int q8, float* ax, float* ay) {
    for (; e + 16 <= end; e += 16) {
        int o0 = csr[e + slot];
        int o1 = csr[e + 4 + slot];
        int o2 = csr[e + 8 + slot];
        int o3 = csr[e + 12 + slot];
        uint2 u0 = *(const uint2*)(Hs8 + (uint)((o0 >> 1) + q8));
        uint2 u1 = *(const uint2*)(Hs8 + (uint)((o1 >> 1) + q8));
        uint2 u2 = *(const uint2*)(Hs8 + (uint)((o2 >> 1) + q8));
        uint2 u3 = *(const uint2*)(Hs8 + (uint)((o3 >> 1) + q8));
        g2_acc(u0, ax, ay); g2_acc(u1, ax, ay);
        g2_acc(u2, ax, ay); g2_acc(u3, ax, ay);
    }
    for (; e + 4 <= end; e += 4) {
        int o = csr[e + slot];
        uint2 u = *(const uint2*)(Hs8 + (uint)((o >> 1) + q8));
        g2_acc(u, ax, ay);
    }
    int rem = end - e;
    if (slot < rem) {
        int o = csr[e + slot];
        uint2 u = *(const uint2*)(Hs8 + (uint)((o >> 1) + q8));
        g2_acc(u, ax, ay);
    }
}

// ---------- gather layer 1: ONE node per 64-thread block (load-balance) ----------
__global__ __launch_bounds__(64) void gather1_kernel(const char* __restrict__ Hs8,
        const int* __restrict__ rowptr, const int* __restrict__ csr,
        const float* __restrict__ dinv, const float* __restrict__ b1,
        uint* __restrict__ A, int n) {
    int i = blockIdx.x;
    int l = threadIdx.x;
    int slot = l >> 4, q = l & 15;
    const int q8 = q * 8;
    float ax[4] = {0.f, 0.f, 0.f, 0.f}, ay[4] = {0.f, 0.f, 0.f, 0.f};
    if (slot == 0) {  // self-loop
        uint2 u = *(const uint2*)(Hs8 + (size_t)i * 128 + q8);
        g2_acc(u, ax, ay);
    }
    gather_fp8(Hs8, csr, rowptr[i], rowptr[i + 1], slot, q8, ax, ay);
#pragma unroll
    for (int k = 0; k < 4; ++k) {
        ax[k] += __shfl_xor(ax[k], 16, 64); ay[k] += __shfl_xor(ay[k], 16, 64);
        ax[k] += __shfl_xor(ax[k], 32, 64); ay[k] += __shfl_xor(ay[k], 32, 64);
    }
    if (slot == 0) {
        float di = dinv[i];
        const float2* bp = (const float2*)(b1 + 8 * q);
        float2 b0 = bp[0], b1v = bp[1], b2v = bp[2], b3v = bp[3];
        uint4 o;
        o.x = packbf2(fmaxf(di * ax[0] + b0.x, 0.f), fmaxf(di * ay[0] + b0.y, 0.f));
        o.y = packbf2(fmaxf(di * ax[1] + b1v.x, 0.f), fmaxf(di * ay[1] + b1v.y, 0.f));
        o.z = packbf2(fmaxf(di * ax[2] + b2v.x, 0.f), fmaxf(di * ay[2] + b2v.y, 0.f));
        o.w = packbf2(fmaxf(di * ax[3] + b3v.x, 0.f), fmaxf(di * ay[3] + b3v.y, 0.f));
        *(uint4*)(A + (size_t)i * 64 + q * 4) = o;
    }
}

// ---------- gather layer 2 (fp8 table) + pooled-merge atomics ----------
__global__ __launch_bounds__(512) void gather2_kernel(const char* __restrict__ Hs8,
        const int* __restrict__ rowptr, const int* __restrict__ csr,
        const float* __restrict__ dinv, const int* __restrict__ batch,
        float* __restrict__ out, int n) {
    __shared__ float sh[8][DIM];
    __shared__ int sgid[8];
    int w = threadIdx.x >> 6;
    int l = threadIdx.x & 63;
    int slot = l >> 4, q = l & 15;
    int i = blockIdx.x * 8 + w;
    if (i < n) {
        const int q8 = q * 8;
        float ax[4] = {0.f, 0.f, 0.f, 0.f}, ay[4] = {0.f, 0.f, 0.f, 0.f};
        if (slot == 0) {  // self-loop
            uint2 u = *(const uint2*)(Hs8 + (size_t)i * 128 + q8);
            g2_acc(u, ax, ay);
        }
        gather_fp8(Hs8, csr, rowptr[i], rowptr[i + 1], slot, q8, ax, ay);
#pragma unroll
        for (int k = 0; k < 4; ++k) {
            ax[k] += __shfl_xor(ax[k], 16, 64); ay[k] += __shfl_xor(ay[k], 16, 64);
            ax[k] += __shfl_xor(ax[k], 32, 64); ay[k] += __shfl_xor(ay[k], 32, 64);
        }
        if (slot == 0) {
            float di = dinv[i];
            float* sp = &sh[w][8 * q];
            sp[0] = di * ax[0]; sp[1] = di * ay[0];
            sp[2] = di * ax[1]; sp[3] = di * ay[1];
            sp[4] = di * ax[2]; sp[5] = di * ay[2];
            sp[6] = di * ax[3]; sp[7] = di * ay[3];
            if (q == 0) sgid[w] = batch[i];
        }
    } else if (l == 0) {
        sgid[w] = -1;
    }
    __syncthreads();
    if (threadIdx.x < DIM) {
        int d = threadIdx.x;
        int curg = -1; float run = 0.0f;
#pragma unroll
        for (int r = 0; r < 8; ++r) {
            int g = sgid[r];
            if (g < 0) continue;
            if (g != curg) {
                if (curg >= 0) atomicAdd(&out[(size_t)curg * DIM + d], run);
                curg = g; run = sh[r][d];
            } else {
                run += sh[r][d];
            }
        }
        if (curg >= 0) atomicAdd(&out[(size_t)curg * DIM + d], run);
    }
}

// ---------- finalize: cnt via binary search on sorted batch ----------
__global__ void fin_kernel(float* __restrict__ out, const int* __restrict__ batch,
                           const float* __restrict__ b2, int n, int nG) {
    int tid = blockIdx.x * blockDim.x + threadIdx.x;
    int g = tid >> 7;
    int d = tid & (DIM - 1);
    if (g >= nG) return;
    int lo = 0, hi = n;
    while (lo < hi) { int m = (lo + hi) >> 1; if (batch[m] < g) lo = m + 1; else hi = m; }
    int s0 = lo;
    hi = n;
    while (lo < hi) { int m = (lo + hi) >> 1; if (batch[m] < g + 1) lo = m + 1; else hi = m; }
    float c = (float)(lo - s0);
    out[tid] = (out[tid] + c * b2[d]) / fmaxf(c, 1.0f);
}

extern "C" void kernel_launch(void* const* d_in, const int* in_sizes, int n_in,
                              void* d_out, int out_size, void* d_ws, size_t ws_size,
                              hipStream_t stream) {
    const float* x     = (const float*)d_in[0];
    const int*   ei    = (const int*)d_in[1];
    const int*   batch = (const int*)d_in[2];
    const float* W1    = (const float*)d_in[3];
    const float* b1    = (const float*)d_in[4];
    const float* W2    = (const float*)d_in[5];
    const float* b2    = (const float*)d_in[6];
    float* out = (float*)d_out;

    const int n  = in_sizes[0] / DIM;   // 50000
    const int nE = in_sizes[1] / 2;     // 800000
    const int nG = out_size / DIM;      // 512

    const int* src = ei;
    const int* dst = ei + nE;

    const int nw4 = (n + 3) >> 2;                 // u8x4-packed words per chunk
    const int WPC = (nw4 + 3) & ~3;
    const size_t packBytes = (size_t)n * 64 * sizeof(uint);   // 12.8 MB (A bf16)
    const size_t partBytes = (size_t)NCH * WPC * 4;           // 12.8 MB
    const size_t ldsBytes  = (size_t)nw4 * 4;                 // 50 KB

    char* ws = (char*)d_ws;
    size_t off = 0;
    auto alloc = [&](size_t bytes) { void* p = ws + off; off = (off + bytes + 255) & ~(size_t)255; return p; };
    // part (CSR phase) aliases Hs8 (6.4MB fp8 tables, both layers); A at +12.8MB.
    size_t bigBytes = partBytes > 2 * packBytes ? partBytes : 2 * packBytes;
    char*  big    = (char*)alloc(bigBytes);
    uint*  part   = (uint*)big;
    char*  Hs8    = big;
    uint*  A      = (uint*)(big + packBytes);
    uint*  gsum   = (uint*)alloc((size_t)NGRP * WPC * 4);     // 400 KB (live through fill)
    int*   deg    = (int*)alloc((size_t)n * 4);
    int*   done   = (int*)alloc(256);
    float* dinv   = (float*)alloc((size_t)n * 4);
    int*   rowptr = (int*)alloc((size_t)(n + 1) * 4);
    int*   bsum   = (int*)alloc(256);
    uint*  Wt1    = (uint*)alloc(8192 * 4);
    uint*  Wt2    = (uint*)alloc(8192 * 4);
    int*   csr    = (int*)alloc((size_t)nE * 4);

    const int B = 256;
    const int nb = (n + 1023) / 1024;  // 49
    const int nwb = (nw4 + B - 1) / B; // 49
    const int outQuads = out_size / 4;

    histprep_kernel<<<NCH + 128, 256, ldsBytes, stream>>>(dst, part, nE, n, WPC,
                                                          W1, W2, Wt1, Wt2, out, outQuads, done);
    reduceA_kernel<<<dim3(nwb, NGRP), B, 0, stream>>>(part, gsum, n, WPC);
    gsumscan_kernel<<<nb, 256, 0, stream>>>(gsum, deg, bsum, rowptr, done, n, nb, WPC);
    scan3_kernel<<<nb, 1024, 0, stream>>>(deg, bsum, rowptr, dinv, n);
    fill_kernel<<<NCH, 256, ldsBytes, stream>>>(src, dst, part, gsum, rowptr, csr, nE, n, WPC);

    // Layer 1: f32 x -> fp8 Hs8 table -> bf16 A (one node per 64-thread block)
    gemm_mfma_kernel<true><<<(n + 63) / 64, 256, 0, stream>>>(x, Wt1, dinv, Hs8, n);
    gather1_kernel<<<n, 64, 0, stream>>>(Hs8, rowptr, csr, dinv, b1, A, n);

    // Layer 2: bf16 A -> fp8 Hs8 table -> pooled out
    gemm_mfma_kernel<false><<<(n + 63) / 64, 256, 0, stream>>>(A, Wt2, dinv, Hs8, n);
    gather2_kernel<<<(n + 7) / 8, 512, 0, stream>>>(Hs8, rowptr, csr, dinv, batch, out, n);

    fin_kernel<<<(nG * DIM + B - 1) / B, B, 0, stream>>>(out, batch, b2, n, nG);
}

// Round 22
// 160.772 us; speedup vs baseline: 1.0564x; 1.0156x over previous
//
#include <hip/hip_runtime.h>

typedef unsigned int uint;
typedef unsigned short ushort_t;
#define DIM 128
#define NCH 256     // edge chunks for CSR build
#define CGRP 32     // chunks per reduce group
#define NGRP (NCH / CGRP)

typedef __attribute__((ext_vector_type(8))) short bf16x8;
typedef __attribute__((ext_vector_type(4))) float f32x4;
typedef __attribute__((ext_vector_type(2))) float f32x2;

// ---------- bf16 pack helpers ----------
__device__ inline uint packbf2(float a, float b) {
    uint ua = __float_as_uint(a), ub = __float_as_uint(b);
    ua = (ua + 0x7fffu + ((ua >> 16) & 1u)) >> 16;
    ub = (ub + 0x7fffu + ((ub >> 16) & 1u)) & 0xffff0000u;
    return ua | ub;
}

// ---------- histprep: hist (blocks 0..NCH-1) + cvtw (NCH..NCH+63) + zero-out/flags ----------
__global__ __launch_bounds__(256) void histprep_kernel(const int* __restrict__ dst,
        uint* __restrict__ part, int nE, int n, int WPC,
        const float* __restrict__ W1, const float* __restrict__ W2,
        uint* __restrict__ Wt1, uint* __restrict__ Wt2,
        float* __restrict__ out, int outQuads, int* __restrict__ done) {
    int b = blockIdx.x;
    if (b >= NCH) {
        int pb = b - NCH;
        if (pb < 64) {
            const float* W = (pb < 32) ? W1 : W2;
            uint* Wt = (pb < 32) ? Wt1 : Wt2;
            int idx = (pb & 31) * 256 + threadIdx.x;  // 0..8191
            int c = idx >> 6;
            int kw = idx & 63;
            float a = W[(2 * kw) * DIM + c];
            float bb = W[(2 * kw + 1) * DIM + c];
            Wt[c * 64 + kw] = packbf2(a, bb);
        } else {
            if (pb == 64 && threadIdx.x == 0) *done = 0;
            int q = (pb - 64) * 256 + threadIdx.x;
            if (q < outQuads) ((float4*)out)[q] = make_float4(0.f, 0.f, 0.f, 0.f);
        }
        return;
    }
    extern __shared__ uint h[];
    const int nw4 = (n + 3) >> 2;
    for (int j = threadIdx.x; j < nw4; j += 256) h[j] = 0;
    __syncthreads();
    int chunk = (((nE + NCH - 1) / NCH) + 3) & ~3;
    int lo = b * chunk;
    int hi = min(nE, lo + chunk);
    int hiA = lo + ((hi - lo) & ~3);
    for (int e = lo + threadIdx.x * 4; e < hiA; e += 1024) {
        int4 v = *(const int4*)(dst + e);
        atomicAdd(&h[v.x >> 2], 1u << ((v.x & 3) * 8));
        atomicAdd(&h[v.y >> 2], 1u << ((v.y & 3) * 8));
        atomicAdd(&h[v.z >> 2], 1u << ((v.z & 3) * 8));
        atomicAdd(&h[v.w >> 2], 1u << ((v.w & 3) * 8));
    }
    for (int e = hiA + threadIdx.x; e < hi; e += 256) {
        int d = dst[e];
        atomicAdd(&h[d >> 2], 1u << ((d & 3) * 8));
    }
    __syncthreads();
    uint* pw = part + (size_t)b * WPC;
    for (int j = threadIdx.x; j < nw4; j += 256) pw[j] = h[j];
}

// ---------- reduceA: per (word-range, chunk-group): intra-group prefix + group sum ----------
__global__ void reduceA_kernel(uint* __restrict__ part, uint* __restrict__ gsum,
                               int n, int WPC) {
    int j = blockIdx.x * blockDim.x + threadIdx.x;
    int nw4 = (n + 3) >> 2;
    if (j >= nw4) return;
    int g = blockIdx.y;
    int c0 = g * CGRP;
    uint run = 0;
#pragma unroll 8
    for (int c = c0; c < c0 + CGRP; ++c) {
        size_t idx = (size_t)c * WPC + j;
        uint v = part[idx];
        part[idx] = run;
        run += v;  // packed u8 add; per-lane totals < 256
    }
    gsum[(size_t)g * WPC + j] = run;
}

__device__ inline int wave_incl_scan(int v) {
    int lane = threadIdx.x & 63;
#pragma unroll
    for (int off = 1; off < 64; off <<= 1) {
        int u = __shfl_up(v, off, 64);
        if (lane >= off) v += u;
    }
    return v;
}

// ---------- gsumscan: gsum chunk-prefix -> deg + block sums + last-block bsum scan ----------
__global__ __launch_bounds__(256) void gsumscan_kernel(uint* __restrict__ gsum,
        int* __restrict__ deg, int* __restrict__ bsum, int* __restrict__ rowptr,
        int* __restrict__ done, int n, int nb, int WPC) {
    __shared__ int wsum[4];
    __shared__ int lastFlag;
    int t = threadIdx.x;
    int j = blockIdx.x * 256 + t;
    int nw4 = (n + 3) >> 2;
    uint run = 0;
    if (j < nw4) {
#pragma unroll
        for (int g = 0; g < NGRP; ++g) {
            size_t idx = (size_t)g * WPC + j;
            uint v = gsum[idx];
            gsum[idx] = run;
            run += v;
        }
        int base = 4 * j;
        deg[base] = (int)(run & 0xffu);
        if (base + 1 < n) deg[base + 1] = (int)((run >> 8) & 0xffu);
        if (base + 2 < n) deg[base + 2] = (int)((run >> 16) & 0xffu);
        if (base + 3 < n) deg[base + 3] = (int)(run >> 24);
    }
    int s = (int)((run & 0xffu) + ((run >> 8) & 0xffu) + ((run >> 16) & 0xffu) + (run >> 24));
#pragma unroll
    for (int off = 32; off > 0; off >>= 1) s += __shfl_down(s, off, 64);
    if ((t & 63) == 0) wsum[t >> 6] = s;
    __syncthreads();
    if (t == 0) {
        bsum[blockIdx.x] = wsum[0] + wsum[1] + wsum[2] + wsum[3];
        __threadfence();
        int r = atomicAdd(done, 1);
        lastFlag = (r == nb - 1);
    }
    __syncthreads();
    if (lastFlag && t < 64) {
        __threadfence();
        int vv = (t < nb) ? bsum[t] : 0;
        int incl = wave_incl_scan(vv);
        if (t < nb) bsum[t] = incl - vv;
        if (t == 63) rowptr[n] = incl;
    }
}

// ---------- scan3: node-level exclusive scan + dinv ----------
__global__ void scan3_kernel(const int* __restrict__ deg, const int* __restrict__ bsum,
                             int* __restrict__ rowptr, float* __restrict__ dinv, int n) {
    __shared__ int wsum[16];
    int t = threadIdx.x;
    int i = blockIdx.x * 1024 + t;
    int v = (i < n) ? deg[i] : 0;
    int incl = wave_incl_scan(v);
    int wid = t >> 6;
    if ((t & 63) == 63) wsum[wid] = incl;
    __syncthreads();
    if (t == 0) {
        int run = 0;
#pragma unroll
        for (int w = 0; w < 16; ++w) { int x = wsum[w]; wsum[w] = run; run += x; }
    }
    __syncthreads();
    if (i < n) {
        rowptr[i] = incl - v + wsum[wid] + bsum[blockIdx.x];
        dinv[i] = rsqrtf((float)(v + 1));  // +1 self-loop
    }
}

// ---------- CSR fill: u8x4 LDS cursor; csr stores BYTE offsets (src*256) ----------
__global__ __launch_bounds__(256) void fill_kernel(const int* __restrict__ src,
                                                   const int* __restrict__ dst,
                                                   const uint* __restrict__ part,
                                                   const uint* __restrict__ gsum,
                                                   const int* __restrict__ rowptr,
                                                   int* __restrict__ csr,
                                                   int nE, int n, int WPC) {
    extern __shared__ uint cur[];
    const int nw4 = (n + 3) >> 2;
    for (int j = threadIdx.x; j < nw4; j += 256) cur[j] = 0;
    __syncthreads();
    const uint* P = part + (size_t)blockIdx.x * WPC;
    const uint* G = gsum + (size_t)(blockIdx.x / CGRP) * WPC;
    int chunk = (((nE + NCH - 1) / NCH) + 3) & ~3;
    int lo = blockIdx.x * chunk;
    int hi = min(nE, lo + chunk);
    int hiA = lo + ((hi - lo) & ~3);
    for (int e = lo + threadIdx.x * 4; e < hiA; e += 1024) {
        int4 d4 = *(const int4*)(dst + e);
        int4 s4 = *(const int4*)(src + e);
        int dd[4] = {d4.x, d4.y, d4.z, d4.w};
        int ss[4] = {s4.x, s4.y, s4.z, s4.w};
#pragma unroll
        for (int k = 0; k < 4; ++k) {
            int d = dd[k];
            uint sh = (uint)(d & 3) * 8u;
            uint old = atomicAdd(&cur[d >> 2], 1u << sh);
            uint local = (old >> sh) & 0xffu;
            uint pre = ((P[d >> 2] >> sh) & 0xffu) + ((G[d >> 2] >> sh) & 0xffu);
            csr[rowptr[d] + (int)pre + (int)local] = ss[k] << 8;
        }
    }
    for (int e = hiA + threadIdx.x; e < hi; e += 256) {
        int d = dst[e];
        uint sh = (uint)(d & 3) * 8u;
        uint old = atomicAdd(&cur[d >> 2], 1u << sh);
        uint local = (old >> sh) & 0xffu;
        uint pre = ((P[d >> 2] >> sh) & 0xffu) + ((G[d >> 2] >> sh) & 0xffu);
        csr[rowptr[d] + (int)pre + (int)local] = src[e] << 8;
    }
}

// ---------- MFMA GEMM: Hs8[r] = fp8( (X[r,:] @ W) * dinv[r] ) ----------
template <bool F32IN>
__global__ __launch_bounds__(256) void gemm_mfma_kernel(const void* __restrict__ Xv,
        const uint* __restrict__ Wt, const float* __restrict__ dinv,
        char* __restrict__ Hs8, int M) {
    __shared__ __align__(16) uint lw[8192];  // 32KB Wt[c][k]
    __shared__ __align__(16) uint lx[4096];  // 16KB X[r][k]
    const int tid = threadIdx.x;
    const int brow = blockIdx.x * 64;
#pragma unroll
    for (int p = 0; p < 16; ++p) {
        int j = p * 256 + tid;
        int r = j >> 6, kw = j & 63;
        int row = brow + r;
        uint v = 0u;
        if (row < M) {
            if (F32IN) {
                float2 f = ((const float2*)Xv)[(size_t)row * 64 + kw];
                v = packbf2(f.x, f.y);
            } else {
                v = ((const uint*)Xv)[(size_t)row * 64 + kw];
            }
        }
        lx[(r << 6) | (((kw >> 2) ^ (r & 7)) << 2) | (kw & 3)] = v;
    }
#pragma unroll
    for (int p = 0; p < 32; ++p) {
        int j = p * 256 + tid;
        int c = j >> 6, kw = j & 63;
        lw[(c << 6) | (((kw >> 2) ^ (c & 7)) << 2) | (kw & 3)] = Wt[j];
    }
    __syncthreads();
    const int wave = tid >> 6, l = tid & 63;
    const int hl = l >> 4;
    const int arow = (wave << 4) | (l & 15);
    f32x4 acc[8];
#pragma unroll
    for (int f = 0; f < 8; ++f) acc[f] = (f32x4){0.f, 0.f, 0.f, 0.f};
#pragma unroll
    for (int ks = 0; ks < 4; ++ks) {
        int ua = (ks << 2) + hl;  // 16B-unit index along K
        bf16x8 af = *(const bf16x8*)&lx[(arow << 6) | ((ua ^ (arow & 7)) << 2)];
#pragma unroll
        for (int f = 0; f < 8; ++f) {
            int bcol = (f << 4) | (l & 15);
            bf16x8 bf = *(const bf16x8*)&lw[(bcol << 6) | ((ua ^ (bcol & 7)) << 2)];
            acc[f] = __builtin_amdgcn_mfma_f32_16x16x32_bf16(af, bf, acc[f], 0, 0, 0);
        }
    }
    // epilogue: D col = lane&15, row = (lane>>4)*4 + reg; fp8 pack of (col, col+1)
    const int rbase = brow + (wave << 4) + (hl << 2);
    float dv[4];
#pragma unroll
    for (int r = 0; r < 4; ++r) dv[r] = (rbase + r < M) ? dinv[rbase + r] : 0.f;
#pragma unroll
    for (int f = 0; f < 8; ++f) {
#pragma unroll
        for (int r = 0; r < 4; ++r) {
            float mine = acc[f][r] * dv[r];
            float other = __shfl_xor(mine, 1, 64);
            if (!(l & 1)) {
                int row = rbase + r;
                if (row < M) {
                    int pk = __builtin_amdgcn_cvt_pk_fp8_f32(mine, other, 0, false);
                    *(ushort_t*)(Hs8 + (size_t)row * 128 + ((f << 4) | (l & 15))) =
                        (ushort_t)(pk & 0xffff);
                }
            }
        }
    }
}

// ---------- fp8 row accumulate: uint2 = 8 dims ----------
__device__ inline void g2_acc(uint2 u, float* ax, float* ay) {
    f32x2 f0 = __builtin_amdgcn_cvt_pk_f32_fp8((int)u.x, false);
    f32x2 f1 = __builtin_amdgcn_cvt_pk_f32_fp8((int)u.x, true);
    f32x2 f2 = __builtin_amdgcn_cvt_pk_f32_fp8((int)u.y, false);
    f32x2 f3 = __builtin_amdgcn_cvt_pk_f32_fp8((int)u.y, true);
    ax[0] += f0.x; ay[0] += f0.y;
    ax[1] += f1.x; ay[1] += f1.y;
    ax[2] += f2.x; ay[2] += f2.y;
    ax[3] += f3.x; ay[3] += f3.y;
}

// ---------- simple fp8 gather loop (r18-proven) ----------
__device__ inline void gather_fp8(const char* __restrict__ Hs8, const int* __restrict__ csr,
                                  int e, int end, int slot, int q8, float* ax, float* ay) {
    for (; e + 16 <= end; e += 16) {
        int o0 = csr[e + slot];
        int o1 = csr[e + 4 + slot];
        int o2 = csr[e + 8 + slot];
        int o3 = csr[e + 12 + slot];
        uint2 u0 = *(const uint2*)(Hs8 + (uint)((o0 >> 1) + q8));
        uint2 u1 = *(const uint2*)(Hs8 + (uint)((o1 >> 1) + q8));
        uint2 u2 = *(const uint2*)(Hs8 + (uint)((o2 >> 1) + q8));
        uint2 u3 = *(const uint2*)(Hs8 + (uint)((o3 >> 1) + q8));
        g2_acc(u0, ax, ay); g2_acc(u1, ax, ay);
        g2_acc(u2, ax, ay); g2_acc(u3, ax, ay);
    }
    for (; e + 4 <= end; e += 4) {
        int o = csr[e + slot];
        uint2 u = *(const uint2*)(Hs8 + (uint)((o >> 1) + q8));
        g2_acc(u, ax, ay);
    }
    int rem = end - e;
    if (slot < rem) {
        int o = csr[e + slot];
        uint2 u = *(const uint2*)(Hs8 + (uint)((o >> 1) + q8));
        g2_acc(u, ax, ay);
    }
}

// ---------- gather layer 1: ONE node per 64-thread block (load-balance) ----------
__global__ __launch_bounds__(64) void gather1_kernel(const char* __restrict__ Hs8,
        const int* __restrict__ rowptr, const int* __restrict__ csr,
        const float* __restrict__ dinv, const float* __restrict__ b1,
        uint* __restrict__ A, int n) {
    int i = blockIdx.x;
    int l = threadIdx.x;
    int slot = l >> 4, q = l & 15;
    const int q8 = q * 8;
    float ax[4] = {0.f, 0.f, 0.f, 0.f}, ay[4] = {0.f, 0.f, 0.f, 0.f};
    if (slot == 0) {  // self-loop
        uint2 u = *(const uint2*)(Hs8 + (size_t)i * 128 + q8);
        g2_acc(u, ax, ay);
    }
    gather_fp8(Hs8, csr, rowptr[i], rowptr[i + 1], slot, q8, ax, ay);
#pragma unroll
    for (int k = 0; k < 4; ++k) {
        ax[k] += __shfl_xor(ax[k], 16, 64); ay[k] += __shfl_xor(ay[k], 16, 64);
        ax[k] += __shfl_xor(ax[k], 32, 64); ay[k] += __shfl_xor(ay[k], 32, 64);
    }
    if (slot == 0) {
        float di = dinv[i];
        const float2* bp = (const float2*)(b1 + 8 * q);
        float2 b0 = bp[0], b1v = bp[1], b2v = bp[2], b3v = bp[3];
        uint4 o;
        o.x = packbf2(fmaxf(di * ax[0] + b0.x, 0.f), fmaxf(di * ay[0] + b0.y, 0.f));
        o.y = packbf2(fmaxf(di * ax[1] + b1v.x, 0.f), fmaxf(di * ay[1] + b1v.y, 0.f));
        o.z = packbf2(fmaxf(di * ax[2] + b2v.x, 0.f), fmaxf(di * ay[2] + b2v.y, 0.f));
        o.w = packbf2(fmaxf(di * ax[3] + b3v.x, 0.f), fmaxf(di * ay[3] + b3v.y, 0.f));
        *(uint4*)(A + (size_t)i * 64 + q * 4) = o;
    }
}

// ---------- gather layer 2: 4 nodes per 256-thread block + pooled-merge atomics ----------
__global__ __launch_bounds__(256) void gather2_kernel(const char* __restrict__ Hs8,
        const int* __restrict__ rowptr, const int* __restrict__ csr,
        const float* __restrict__ dinv, const int* __restrict__ batch,
        float* __restrict__ out, int n) {
    __shared__ float sh[4][DIM];
    __shared__ int sgid[4];
    int w = threadIdx.x >> 6;
    int l = threadIdx.x & 63;
    int slot = l >> 4, q = l & 15;
    int i = blockIdx.x * 4 + w;
    if (i < n) {
        const int q8 = q * 8;
        float ax[4] = {0.f, 0.f, 0.f, 0.f}, ay[4] = {0.f, 0.f, 0.f, 0.f};
        if (slot == 0) {  // self-loop
            uint2 u = *(const uint2*)(Hs8 + (size_t)i * 128 + q8);
            g2_acc(u, ax, ay);
        }
        gather_fp8(Hs8, csr, rowptr[i], rowptr[i + 1], slot, q8, ax, ay);
#pragma unroll
        for (int k = 0; k < 4; ++k) {
            ax[k] += __shfl_xor(ax[k], 16, 64); ay[k] += __shfl_xor(ay[k], 16, 64);
            ax[k] += __shfl_xor(ax[k], 32, 64); ay[k] += __shfl_xor(ay[k], 32, 64);
        }
        if (slot == 0) {
            float di = dinv[i];
            float* sp = &sh[w][8 * q];
            sp[0] = di * ax[0]; sp[1] = di * ay[0];
            sp[2] = di * ax[1]; sp[3] = di * ay[1];
            sp[4] = di * ax[2]; sp[5] = di * ay[2];
            sp[6] = di * ax[3]; sp[7] = di * ay[3];
            if (q == 0) sgid[w] = batch[i];
        }
    } else if (l == 0) {
        sgid[w] = -1;
    }
    __syncthreads();
    if (threadIdx.x < DIM) {
        int d = threadIdx.x;
        int curg = -1; float run = 0.0f;
#pragma unroll
        for (int r = 0; r < 4; ++r) {
            int g = sgid[r];
            if (g < 0) continue;
            if (g != curg) {
                if (curg >= 0) atomicAdd(&out[(size_t)curg * DIM + d], run);
                curg = g; run = sh[r][d];
            } else {
                run += sh[r][d];
            }
        }
        if (curg >= 0) atomicAdd(&out[(size_t)curg * DIM + d], run);
    }
}

// ---------- finalize: cnt via binary search on sorted batch ----------
__global__ void fin_kernel(float* __restrict__ out, const int* __restrict__ batch,
                           const float* __restrict__ b2, int n, int nG) {
    int tid = blockIdx.x * blockDim.x + threadIdx.x;
    int g = tid >> 7;
    int d = tid & (DIM - 1);
    if (g >= nG) return;
    int lo = 0, hi = n;
    while (lo < hi) { int m = (lo + hi) >> 1; if (batch[m] < g) lo = m + 1; else hi = m; }
    int s0 = lo;
    hi = n;
    while (lo < hi) { int m = (lo + hi) >> 1; if (batch[m] < g + 1) lo = m + 1; else hi = m; }
    float c = (float)(lo - s0);
    out[tid] = (out[tid] + c * b2[d]) / fmaxf(c, 1.0f);
}

extern "C" void kernel_launch(void* const* d_in, const int* in_sizes, int n_in,
                              void* d_out, int out_size, void* d_ws, size_t ws_size,
                              hipStream_t stream) {
    const float* x     = (const float*)d_in[0];
    const int*   ei    = (const int*)d_in[1];
    const int*   batch = (const int*)d_in[2];
    const float* W1    = (const float*)d_in[3];
    const float* b1    = (const float*)d_in[4];
    const float* W2    = (const float*)d_in[5];
    const float* b2    = (const float*)d_in[6];
    float* out = (float*)d_out;

    const int n  = in_sizes[0] / DIM;   // 50000
    const int nE = in_sizes[1] / 2;     // 800000
    const int nG = out_size / DIM;      // 512

    const int* src = ei;
    const int* dst = ei + nE;

    const int nw4 = (n + 3) >> 2;                 // u8x4-packed words per chunk
    const int WPC = (nw4 + 3) & ~3;
    const size_t packBytes = (size_t)n * 64 * sizeof(uint);   // 12.8 MB (A bf16)
    const size_t partBytes = (size_t)NCH * WPC * 4;           // 12.8 MB
    const size_t ldsBytes  = (size_t)nw4 * 4;                 // 50 KB

    char* ws = (char*)d_ws;
    size_t off = 0;
    auto alloc = [&](size_t bytes) { void* p = ws + off; off = (off + bytes + 255) & ~(size_t)255; return p; };
    // part (CSR phase) aliases Hs8 (6.4MB fp8 tables, both layers); A at +12.8MB.
    size_t bigBytes = partBytes > 2 * packBytes ? partBytes : 2 * packBytes;
    char*  big    = (char*)alloc(bigBytes);
    uint*  part   = (uint*)big;
    char*  Hs8    = big;
    uint*  A      = (uint*)(big + packBytes);
    uint*  gsum   = (uint*)alloc((size_t)NGRP * WPC * 4);     // 400 KB (live through fill)
    int*   deg    = (int*)alloc((size_t)n * 4);
    int*   done   = (int*)alloc(256);
    float* dinv   = (float*)alloc((size_t)n * 4);
    int*   rowptr = (int*)alloc((size_t)(n + 1) * 4);
    int*   bsum   = (int*)alloc(256);
    uint*  Wt1    = (uint*)alloc(8192 * 4);
    uint*  Wt2    = (uint*)alloc(8192 * 4);
    int*   csr    = (int*)alloc((size_t)nE * 4);

    const int B = 256;
    const int nb = (n + 1023) / 1024;  // 49
    const int nwb = (nw4 + B - 1) / B; // 49
    const int outQuads = out_size / 4;

    histprep_kernel<<<NCH + 128, 256, ldsBytes, stream>>>(dst, part, nE, n, WPC,
                                                          W1, W2, Wt1, Wt2, out, outQuads, done);
    reduceA_kernel<<<dim3(nwb, NGRP), B, 0, stream>>>(part, gsum, n, WPC);
    gsumscan_kernel<<<nb, 256, 0, stream>>>(gsum, deg, bsum, rowptr, done, n, nb, WPC);
    scan3_kernel<<<nb, 1024, 0, stream>>>(deg, bsum, rowptr, dinv, n);
    fill_kernel<<<NCH, 256, ldsBytes, stream>>>(src, dst, part, gsum, rowptr, csr, nE, n, WPC);

    // Layer 1: f32 x -> fp8 Hs8 table -> bf16 A (one node per 64-thread block)
    gemm_mfma_kernel<true><<<(n + 63) / 64, 256, 0, stream>>>(x, Wt1, dinv, Hs8, n);
    gather1_kernel<<<n, 64, 0, stream>>>(Hs8, rowptr, csr, dinv, b1, A, n);

    // Layer 2: bf16 A -> fp8 Hs8 table -> pooled out (4 nodes per block)
    gemm_mfma_kernel<false><<<(n + 63) / 64, 256, 0, stream>>>(A, Wt2, dinv, Hs8, n);
    gather2_kernel<<<(n + 3) / 4, 256, 0, stream>>>(Hs8, rowptr, csr, dinv, batch, out, n);

    fin_kernel<<<(nG * DIM + B - 1) / B, B, 0, stream>>>(out, batch, b2, n, nG);
}